// Round 16
// baseline (3560.313 us; speedup 1.0000x reference)
//
#include <hip/hip_runtime.h>
#include <cstdint>

// Problem constants
#define Bsz 2048
#define Ssz 50
#define Esz 256
#define Hsz 512
#define Wsz 256
#define Lsz 50
#define Vsz 51
#define KI 16    // paired k-iterations (each covers hi[kc], lo[kc+16])
#define CH 10    // steps per blend/sample chunk
#define GFRAGC2 ((size_t)32 * 128 * 512)  // f16 elems per h/W gates pack (4MB)

// JAX RNG semantics: 1 = threefry_partitionable (jax >= 0.4.36 default), 0 = original
#define JAX_THREEFRY_PARTITIONABLE 1

typedef _Float16 f16;
typedef _Float16 f16x8 __attribute__((ext_vector_type(8)));
typedef float f32x4 __attribute__((ext_vector_type(4)));

// ---------------- threefry2x32 (20 rounds), key words (k0,k1) ----------------
__host__ __device__ __forceinline__ void threefry2x32_hd(
    unsigned k0, unsigned k1, unsigned x0, unsigned x1,
    unsigned& o0, unsigned& o1) {
  unsigned ks2 = k0 ^ k1 ^ 0x1BD11BDAu;
  x0 += k0; x1 += k1;
#define TF_RND(r) { x0 += x1; x1 = (x1 << (r)) | (x1 >> (32 - (r))); x1 ^= x0; }
  TF_RND(13) TF_RND(15) TF_RND(26) TF_RND(6)
  x0 += k1; x1 += ks2 + 1u;
  TF_RND(17) TF_RND(29) TF_RND(16) TF_RND(24)
  x0 += ks2; x1 += k0 + 2u;
  TF_RND(13) TF_RND(15) TF_RND(26) TF_RND(6)
  x0 += k0; x1 += k1 + 3u;
  TF_RND(17) TF_RND(29) TF_RND(16) TF_RND(24)
  x0 += k1; x1 += ks2 + 4u;
  TF_RND(13) TF_RND(15) TF_RND(26) TF_RND(6)
  x0 += ks2; x1 += k0 + 5u;
#undef TF_RND
  o0 = x0; o1 = x1;
}

// ---- prep: gates W pack, dual-acc fp16x3 layout ----
// dst[(kc*128 + ntile)*512 + l*8 + e]: kc in [0,16) = Whi, kc in [16,32) =
// Wlo*2048 (same k range).  k = (kc&15)*32 + kg*8 + e; n' = j*4+g.
__global__ __launch_bounds__(512) void prep_gfrag(const float* __restrict__ Whh,
                                                  f16* __restrict__ dst) {
  int blk = blockIdx.x;            // ntile*32 + kc   (grid 128*32 = 4096)
  int ntile = blk >> 5, kc = blk & 31;
  int t = threadIdx.x;             // 512 = l*8 + e
  int l = t >> 3, e = t & 7;
  int c = l & 15, kg = l >> 4;
  int n = ntile * 16 + c;          // n' in [0,2048)
  int k = (kc & 15) * 32 + kg * 8 + e;
  int j = n >> 2, g = n & 3;
  float w = Whh[(size_t)(g * 512 + j) * 512 + k];
  f16 hi = (f16)w;
  float lo = w - (float)hi;
  f16 val = (kc < 16) ? hi : (f16)(lo * 2048.0f);
  dst[((size_t)kc * 128 + ntile) * 512 + t] = val;
}

// ---- prep: blend W pack: [kc 0..31][wtile 0..15][512]; kc>=16 = Wlo*2048 ----
__global__ __launch_bounds__(512) void prep_bfrag(const float* __restrict__ Wm,
                                                  f16* __restrict__ dst) {
  int blk = blockIdx.x;            // wtile*32 + kc   (grid 16*32 = 512)
  int wtile = blk >> 5, kc = blk & 31;
  int t = threadIdx.x;
  int l = t >> 3, e = t & 7;
  int c = l & 15, kg = l >> 4;
  int n = wtile * 16 + c;          // w in [0,256)
  int k = (kc & 15) * 32 + kg * 8 + e;
  float w = Wm[(size_t)n * 512 + k];
  f16 hi = (f16)w;
  float lo = w - (float)hi;
  f16 val = (kc < 16) ? hi : (f16)(lo * 2048.0f);
  dst[((size_t)kc * 16 + wtile) * 512 + t] = val;
}

// ---------------- prep: encInP[v][j*4+g] = emb[v].Wih[g*512+j] + bih + bhh ---
__global__ __launch_bounds__(256) void prep_encin(
    const float* __restrict__ emb, const float* __restrict__ Wih,
    const float* __restrict__ bih, const float* __restrict__ bhh,
    float* __restrict__ encInP) {
  int wid = blockIdx.x * 4 + (threadIdx.x >> 6);
  int lane = threadIdx.x & 63;
  if (wid >= Vsz * 2048) return;
  int v = wid >> 11, col = wid & 2047;
  float4 e = ((const float4*)emb)[v * 64 + lane];
  float4 w = ((const float4*)Wih)[col * 64 + lane];
  float d = e.x * w.x + e.y * w.y + e.z * w.z + e.w * w.w;
  for (int off = 32; off; off >>= 1) d += __shfl_xor(d, off);
  if (lane == 0) {
    int g = col >> 9, j = col & 511;
    encInP[(size_t)v * 2048 + j * 4 + g] = d + bih[col] + bhh[col];
  }
}

// ---------------- prep: dbiasP[j*4+g] = dec_bih + dec_bhh ----------------
__global__ __launch_bounds__(256) void prep_dbias(const float* __restrict__ a,
                                                  const float* __restrict__ b,
                                                  float* __restrict__ dst) {
  int col = blockIdx.x * 256 + threadIdx.x;  // < 2048
  int g = col >> 9, j = col & 511;
  dst[j * 4 + g] = a[col] + b[col];
}

// ---------------- fused gates MFMA GEMM + LSTM cell (r12/r8 config) ----------
// Dual-acc fp16x3: acc1 += hi*Whi + lo*Whi, acc2 += hi*(Wlo*2048);
// C = acc1 + acc2*2^-11.  Tile 64b x 128n', grid 512 = 2 blocks/CU -- the
// best-measured gates config (r12 3342 vs A4B4's r13 3372 / r15 3523).
// Block: 4 waves (2m x 2n); wave = 32b x 64n'.  XCD swizzle: XCD x owns
// b-rows [256x,256x+256) (A producer/consumer L2-local across steps).
__global__ __launch_bounds__(256, 2) void gates_mfma(
    const f16* __restrict__ Afrag,   // h16' [32 kc][128 mt][64 lane][8]
    const f16* __restrict__ Bfrag,   // W'   [32 kc][128 nt][64 lane][8]
    const float* __restrict__ addtab, const int* __restrict__ input, int tstep,
    f16* __restrict__ Aout,          // next h16', same layout
    float* __restrict__ cio) {       // [2048][512] f32
  __shared__ float Cst[64][132];
  const int t = threadIdx.x;
  const int lane = t & 63;
  const int wid = t >> 6;
  const int wm = wid >> 1, wn = wid & 1;
  const int bid = blockIdx.x;
  const int xcd = bid & 7, loc = bid >> 3;          // loc in [0,64)
  const int mblk = xcd * 4 + (loc >> 4);            // 0..31 (64-b tiles)
  const int nblk = loc & 15;                        // 0..15 (128-n' tiles)

  const f16* Ab = Afrag + (size_t)(mblk * 4 + wm * 2) * 512 + lane * 8;
  const f16* Bb = Bfrag + (size_t)(nblk * 8 + wn * 4) * 512 + lane * 8;

  f32x4 acc1[2][4], acc2[2][4];
  {
    f32x4 z = {0.f, 0.f, 0.f, 0.f};
#pragma unroll
    for (int i = 0; i < 2; ++i)
#pragma unroll
      for (int j = 0; j < 4; ++j) { acc1[i][j] = z; acc2[i][j] = z; }
  }

  f16x8 pah[2], pal[2], pbh[4], pbl[4];
  f16x8 qah[2], qal[2], qbh[4], qbl[4];

#define GLOAD(AH_, AL_, BH_, BL_, ki_)                                        \
  {                                                                           \
    const f16* ak = Ab + (size_t)(ki_)*65536;                                 \
    const f16* bk = Bb + (size_t)(ki_)*65536;                                 \
    _Pragma("unroll")                                                         \
    for (int q = 0; q < 2; ++q) {                                             \
      AH_[q] = *(const f16x8*)(ak + q * 512);                                 \
      AL_[q] = *(const f16x8*)(ak + (size_t)16 * 65536 + q * 512);            \
    }                                                                         \
    _Pragma("unroll")                                                         \
    for (int q = 0; q < 4; ++q) {                                             \
      BH_[q] = *(const f16x8*)(bk + q * 512);                                 \
      BL_[q] = *(const f16x8*)(bk + (size_t)16 * 65536 + q * 512);            \
    }                                                                         \
  }
#define GMM(AH_, AL_, BH_, BL_)                                               \
  {                                                                           \
    _Pragma("unroll")                                                         \
    for (int mt = 0; mt < 2; ++mt)                                            \
      _Pragma("unroll")                                                       \
      for (int nt = 0; nt < 4; ++nt)                                          \
        acc1[mt][nt] = __builtin_amdgcn_mfma_f32_16x16x32_f16(                \
            AH_[mt], BH_[nt], acc1[mt][nt], 0, 0, 0);                         \
    _Pragma("unroll")                                                         \
    for (int mt = 0; mt < 2; ++mt)                                            \
      _Pragma("unroll")                                                       \
      for (int nt = 0; nt < 4; ++nt)                                          \
        acc1[mt][nt] = __builtin_amdgcn_mfma_f32_16x16x32_f16(                \
            AL_[mt], BH_[nt], acc1[mt][nt], 0, 0, 0);                         \
    _Pragma("unroll")                                                         \
    for (int mt = 0; mt < 2; ++mt)                                            \
      _Pragma("unroll")                                                       \
      for (int nt = 0; nt < 4; ++nt)                                          \
        acc2[mt][nt] = __builtin_amdgcn_mfma_f32_16x16x32_f16(                \
            AH_[mt], BL_[nt], acc2[mt][nt], 0, 0, 0);                         \
  }

  GLOAD(pah, pal, pbh, pbl, 0)
#pragma unroll 1
  for (int ki = 0; ki < KI; ki += 2) {
    GLOAD(qah, qal, qbh, qbl, ki + 1)
    GMM(pah, pal, pbh, pbl)
    if (ki + 2 < KI) GLOAD(pah, pal, pbh, pbl, ki + 2)
    GMM(qah, qal, qbh, qbl)
  }
#undef GLOAD
#undef GMM

  // ---- epilogue: combine accs, restage via LDS (Cst 34KB; 2 blocks/CU) ----
#pragma unroll
  for (int mt = 0; mt < 2; ++mt)
#pragma unroll
    for (int nt = 0; nt < 4; ++nt)
#pragma unroll
      for (int rg = 0; rg < 4; ++rg)
        Cst[wm * 32 + mt * 16 + (lane >> 4) * 4 + rg]
           [wn * 64 + nt * 16 + (lane & 15)] =
            acc1[mt][nt][rg] + acc2[mt][nt][rg] * (1.0f / 2048.0f);
  __syncthreads();

  const int bloc = t & 63, jg = t >> 6;
  const int bg = mblk * 64 + bloc;
  const float* arow = input
      ? addtab + (size_t)input[(size_t)bg * Ssz + tstep] * 2048
      : addtab;

  const int j0 = nblk * 32 + jg * 8;   // 8 j's per thread
  float* cp = cio + (size_t)bg * 512 + j0;
  float4 cv0 = *(const float4*)(cp);
  float4 cv1 = *(const float4*)(cp + 4);
  float cin[8] = {cv0.x, cv0.y, cv0.z, cv0.w, cv1.x, cv1.y, cv1.z, cv1.w};
  float cn[8], hv[8];
#pragma unroll
  for (int jj = 0; jj < 8; ++jj) {
    float4 gq = *(const float4*)(&Cst[bloc][jg * 32 + jj * 4]);
    float4 av = *(const float4*)(arow + (size_t)(j0 + jj) * 4);
    float gi = gq.x + av.x;
    float gf = gq.y + av.y;
    float gg = gq.z + av.z;
    float go = gq.w + av.w;
    float si = 1.0f / (1.0f + expf(-gi));
    float sf = 1.0f / (1.0f + expf(-gf));
    float sg = tanhf(gg);
    float so = 1.0f / (1.0f + expf(-go));
    float c2 = sf * cin[jj] + si * sg;
    cn[jj] = c2;
    hv[jj] = so * tanhf(c2);
  }
  *(float4*)(cp)     = make_float4(cn[0], cn[1], cn[2], cn[3]);
  *(float4*)(cp + 4) = make_float4(cn[4], cn[5], cn[6], cn[7]);

  f16x8 hi8, lo8;
#pragma unroll
  for (int jj = 0; jj < 8; ++jj) {
    f16 hi = (f16)hv[jj];
    hi8[jj] = hi;
    lo8[jj] = (f16)(hv[jj] - (float)hi);
  }
  const int kcH = j0 >> 5;             // 0..15
  const int kg = (j0 >> 3) & 3;
  size_t base = (((size_t)kcH * 128 + (bg >> 4)) * 64 + kg * 16 + (bg & 15)) * 8;
  *(f16x8*)(Aout + base)                       = hi8;  // kc 0..15: hi
  *(f16x8*)(Aout + base + (size_t)16 * 65536)  = lo8;  // kc 16..31: lo
}

// ---------------- batched blend MFMA: CH steps in one dispatch ---------------
// Dual-acc fp16x3.  XCD mapping ALIGNED with gates h-row ownership.
// EPILOGUE CHANGE (bit-identical): stores exp(2*acc) instead of acc.  Both
// outputs (b1 and b2c) are consumed ONLY by the sampler as exp(2*x); applying
// __expf to the same f32 value the sampler would have loaded gives the exact
// same bits, and moves ~13K transcendentals/block/chunk out of sample_chunk.
__global__ __launch_bounds__(256) void blend_big(
    const f16* __restrict__ hChunk, const f16* __restrict__ Wb,
    float* __restrict__ outBase, int stepStride, int rowStride) {
  const int t = threadIdx.x, lane = t & 63, wid = t >> 6;
  const int wm = wid >> 1, wn = wid & 1;
  const int bid = blockIdx.x;
  const int xcd = bid & 7;
  const int r1 = bid >> 3;
  const int nblk = r1 & 7;             // 0..7  (32-w tiles)
  const int r2 = r1 >> 3;
  const int mrem = r2 & 3;
  const int s = r2 >> 2;               // step within chunk
  const int mblkL = xcd * 4 + mrem;    // 0..31 (64-b tiles), XCD-aligned
  const f16* Ab = hChunk + (size_t)s * GFRAGC2
                + (size_t)(mblkL * 4 + wm * 2) * 512 + lane * 8;
  const f16* Bb = Wb + (size_t)(nblk * 2 + wn) * 512 + lane * 8;

  f32x4 acc1[2], acc2[2];
  {
    f32x4 z = {0.f, 0.f, 0.f, 0.f};
    acc1[0] = z; acc1[1] = z; acc2[0] = z; acc2[1] = z;
  }
  f16x8 pah[2], pal[2], pbh, pbl, qah[2], qal[2], qbh, qbl;

#define BLOAD(AH_, AL_, BH_, BL_, ki_)                                        \
  {                                                                           \
    const f16* ak = Ab + (size_t)(ki_)*65536;                                 \
    const f16* bk = Bb + (size_t)(ki_)*8192;                                  \
    _Pragma("unroll")                                                         \
    for (int q = 0; q < 2; ++q) {                                             \
      AH_[q] = *(const f16x8*)(ak + q * 512);                                 \
      AL_[q] = *(const f16x8*)(ak + (size_t)16 * 65536 + q * 512);            \
    }                                                                         \
    BH_ = *(const f16x8*)(bk);                                                \
    BL_ = *(const f16x8*)(bk + (size_t)16 * 8192);                            \
  }
#define BMM(AH_, AL_, BH_, BL_)                                               \
  {                                                                           \
    _Pragma("unroll")                                                         \
    for (int mt = 0; mt < 2; ++mt)                                            \
      acc1[mt] = __builtin_amdgcn_mfma_f32_16x16x32_f16(                      \
          AH_[mt], BH_, acc1[mt], 0, 0, 0);                                   \
    _Pragma("unroll")                                                         \
    for (int mt = 0; mt < 2; ++mt)                                            \
      acc1[mt] = __builtin_amdgcn_mfma_f32_16x16x32_f16(                      \
          AL_[mt], BH_, acc1[mt], 0, 0, 0);                                   \
    _Pragma("unroll")                                                         \
    for (int mt = 0; mt < 2; ++mt)                                            \
      acc2[mt] = __builtin_amdgcn_mfma_f32_16x16x32_f16(                      \
          AH_[mt], BL_, acc2[mt], 0, 0, 0);                                   \
  }

  BLOAD(pah, pal, pbh, pbl, 0)
#pragma unroll 1
  for (int ki = 0; ki < KI; ki += 2) {
    BLOAD(qah, qal, qbh, qbl, ki + 1)
    BMM(pah, pal, pbh, pbl)
    if (ki + 2 < KI) BLOAD(pah, pal, pbh, pbl, ki + 2)
    BMM(qah, qal, qbh, qbl)
  }
#undef BLOAD
#undef BMM

  const int r = lane & 15, rg4 = (lane >> 4) * 4;
  float* ob = outBase + (size_t)s * stepStride;
#pragma unroll
  for (int mt = 0; mt < 2; ++mt)
#pragma unroll
    for (int rg = 0; rg < 4; ++rg) {
      int b = mblkL * 64 + wm * 32 + mt * 16 + rg4 + rg;
      int w = nblk * 32 + wn * 16 + r;
      float val = acc1[mt][rg] + acc2[mt][rg] * (1.0f / 2048.0f);
      ob[(size_t)b * rowStride + w] = __expf(2.0f * val);   // E = e^{2*blend}
    }
}

// ---------------- decoder c0 = last encoder h (reconstruct hi+lo) ------------
__global__ __launch_bounds__(256) void dec_cinit(const f16* __restrict__ hE,
                                                 float* __restrict__ cD) {
  int idx = blockIdx.x * 256 + threadIdx.x;  // < 2048*512
  int b = idx >> 9, j = idx & 511;
  size_t base = (((size_t)(j >> 5) * 128 + (b >> 4)) * 64
                 + ((j >> 3) & 3) * 16 + (b & 15)) * 8 + (j & 7);
  cD[idx] = (float)hE[base] + (float)hE[base + (size_t)16 * 65536];
}

// ---------------- fused chunk sampling v5: 9-wave, pre-exp inputs ------------
// b1/b2c now hold E = e^{2*x} (computed in blend from the same f32 bits ->
// values identical to in-kernel exp).  576 thr = 9 waves: waves 0..7 compute
// step kk+1's scores (rows s += 8, was /7 -- row assignment doesn't change
// per-row math), wave 8 runs step kk's softmax+gumbel+mask.
// tanh(b1+b2) = 1 - 2/(E1*E2+1): per element fma, rcp, fma, fma.
__global__ __launch_bounds__(576) void sample_chunk(
    const float* __restrict__ b1, const float* __restrict__ b2c,
    const float* __restrict__ vt, unsigned long long* __restrict__ mask,
    float* __restrict__ probs, float* __restrict__ tour, int k0) {
  __shared__ float e1s[Ssz * Wsz];   // 50 KB: e^{2*b1} (copied, already exp'd)
  __shared__ float scbuf[2][52];
  const int t = threadIdx.x, b = blockIdx.x;
  const int wid = t >> 6, lane = t & 63;
  {
    const float4* src = (const float4*)(b1 + (size_t)b * Ssz * Wsz);
    for (int i = t; i < (Ssz * Wsz) / 4; i += 576)
      ((float4*)e1s)[i] = src[i];
  }
  const float vtr0 = vt[lane], vtr1 = vt[lane + 64];
  const float vtr2 = vt[lane + 128], vtr3 = vt[lane + 192];
  unsigned long long m = (wid == 8) ? mask[b] : 0ull;
  __syncthreads();

#define SCORE_ROWS(step_, dst_)                                               \
  {                                                                           \
    const float* b2p = b2c + ((size_t)(step_) * Bsz + b) * Wsz;               \
    float e20 = b2p[lane];                                                    \
    float e21 = b2p[lane + 64];                                               \
    float e22 = b2p[lane + 128];                                              \
    float e23 = b2p[lane + 192];                                              \
    for (int s = wid; s < Ssz; s += 8) {                                      \
      const float* row = e1s + s * Wsz;                                       \
      float r0 = __frcp_rn(fmaf(row[lane], e20, 1.0f));                       \
      float v = vtr0 * fmaf(-2.0f, r0, 1.0f);                                 \
      float r1 = __frcp_rn(fmaf(row[lane + 64], e21, 1.0f));                  \
      v += vtr1 * fmaf(-2.0f, r1, 1.0f);                                      \
      float r2 = __frcp_rn(fmaf(row[lane + 128], e22, 1.0f));                 \
      v += vtr2 * fmaf(-2.0f, r2, 1.0f);                                      \
      float r3 = __frcp_rn(fmaf(row[lane + 192], e23, 1.0f));                 \
      v += vtr3 * fmaf(-2.0f, r3, 1.0f);                                      \
      for (int off = 32; off; off >>= 1) v += __shfl_xor(v, off);             \
      if (lane == 0) (dst_)[s] = v;                                           \
    }                                                                         \
  }

  // prologue: waves 0..7 compute step 0 into scbuf[0]
  if (wid < 8) SCORE_ROWS(0, scbuf[0])
  __syncthreads();

#pragma unroll 1
  for (int kk = 0; kk < CH; ++kk) {
    if (wid < 8) {
      if (kk + 1 < CH) SCORE_ROWS(kk + 1, scbuf[(kk + 1) & 1])
    } else {
      const float* sc = scbuf[kk & 1];
      const int stepk = k0 + kk;
      float x = (lane < Ssz) ? sc[lane] : -INFINITY;
      if (lane < Ssz && ((m >> lane) & 1ull)) x = -100000.0f;
      float mv = x;
      for (int off = 32; off; off >>= 1) mv = fmaxf(mv, __shfl_xor(mv, off));
      float sh = x - mv;
      float e = (lane < Ssz) ? expf(sh) : 0.f;
      float ssum = e;
      for (int off = 32; off; off >>= 1) ssum += __shfl_xor(ssum, off);
      float lg = logf(ssum);
      float logp = sh - lg;
      if (lane < Ssz) probs[(size_t)b * (Lsz * Ssz) + stepk * Ssz + lane] = logp;

      unsigned kA, kB;
#if JAX_THREEFRY_PARTITIONABLE
      threefry2x32_hd(0u, 42u, 0u, (unsigned)stepk, kA, kB);
#else
      {
        unsigned a0, a1, c0, c1;
        int k = stepk;
        if (k < 25) {
          threefry2x32_hd(0u, 42u, 2u * k,      2u * k + 50u, a0, a1); kA = a0;
          threefry2x32_hd(0u, 42u, 2u * k + 1u, 2u * k + 51u, c0, c1); kB = c0;
        } else {
          threefry2x32_hd(0u, 42u, 2u * k - 50u, 2u * k,      a0, a1); kA = a1;
          threefry2x32_hd(0u, 42u, 2u * k - 49u, 2u * k + 1u, c0, c1); kB = c1;
        }
      }
#endif
      float val = -INFINITY;
      if (lane < Ssz) {
        unsigned j = (unsigned)(b * Ssz + lane);
        unsigned o0, o1, bits;
#if JAX_THREEFRY_PARTITIONABLE
        threefry2x32_hd(kA, kB, 0u, j, o0, o1);
        bits = o0 ^ o1;
#else
        if (j < 51200u) { threefry2x32_hd(kA, kB, j, j + 51200u, o0, o1); bits = o0; }
        else           { threefry2x32_hd(kA, kB, j - 51200u, j, o0, o1); bits = o1; }
#endif
        float f = __uint_as_float((bits >> 9) | 0x3F800000u) - 1.0f;
        float u = fmaxf(1.17549435e-38f, f + 1.17549435e-38f);
        val = logp - logf(-logf(u));
      }
      int idx = lane;
      for (int off = 32; off; off >>= 1) {
        float ov = __shfl_xor(val, off);
        int oi = __shfl_xor(idx, off);
        if (ov > val || (ov == val && oi < idx)) { val = ov; idx = oi; }
      }
      if (lane == 0) tour[(size_t)b * Lsz + stepk] = (float)idx;
      m |= (1ull << idx);
    }
    __syncthreads();
  }
#undef SCORE_ROWS
  if (wid == 8 && lane == 0) mask[b] = m;
}

extern "C" void kernel_launch(void* const* d_in, const int* in_sizes, int n_in,
                              void* d_out, int out_size, void* d_ws, size_t ws_size,
                              hipStream_t stream) {
  (void)in_sizes; (void)n_in; (void)out_size; (void)ws_size;
  const int*   input = (const int*)d_in[0];
  const float* emb   = (const float*)d_in[1];
  const float* eWih  = (const float*)d_in[2];
  const float* eWhh  = (const float*)d_in[3];
  const float* ebih  = (const float*)d_in[4];
  const float* ebhh  = (const float*)d_in[5];
  /* d_in[6] dec_Wih unused: decoder input is always zero */
  const float* dWhh  = (const float*)d_in[7];
  const float* dbih  = (const float*)d_in[8];
  const float* dbhh  = (const float*)d_in[9];
  const float* W1    = (const float*)d_in[10];
  const float* W2    = (const float*)d_in[11];
  const float* vt    = (const float*)d_in[12];
  float* outF = (float*)d_out;

  float* wsf = (float*)d_ws;
  size_t o = 0;
  const size_t BFRAG = (size_t)32 * 16 * 512;   // f16 count (blend W pack)
  f16* BfE = (f16*)(wsf + o); o += GFRAGC2 / 2;  // enc gates W pack (4MB)
  f16* BfD = (f16*)(wsf + o); o += GFRAGC2 / 2;  // dec gates W pack
  f16* Bb1 = (f16*)(wsf + o); o += BFRAG / 2;    // W1 blend pack
  f16* Bb2 = (f16*)(wsf + o); o += BFRAG / 2;    // W2 blend pack
  float* encInP = wsf + o; o += (size_t)Vsz * 2048;
  float* dbiasP = wsf + o; o += 2048;
  f16* hZero = (f16*)(wsf + o); o += GFRAGC2 / 2;          // zero h frags
  f16* hBuf  = (f16*)(wsf + o); o += CH * (GFRAGC2 / 2);   // CH rolling h frags
  float* cE  = wsf + o; o += (size_t)Bsz * Hsz;            // enc c, then dec c
  float* b2c = wsf + o; o += (size_t)CH * Bsz * Wsz;       // dec b2 chunk (exp'd)
  float* b1  = wsf + o; o += (size_t)Bsz * Ssz * Wsz;      // enc blend (exp'd)
  unsigned long long* maskp = (unsigned long long*)(wsf + o); o += Bsz * 2;

  hipMemsetAsync(hZero, 0, GFRAGC2 * 2, stream);
  hipMemsetAsync(cE, 0, (size_t)Bsz * Hsz * 4, stream);
  hipMemsetAsync(maskp, 0, (size_t)Bsz * 8, stream);

  prep_gfrag<<<128 * 32, 512, 0, stream>>>(eWhh, BfE);
  prep_gfrag<<<128 * 32, 512, 0, stream>>>(dWhh, BfD);
  prep_bfrag<<<16 * 32, 512, 0, stream>>>(W1, Bb1);
  prep_bfrag<<<16 * 32, 512, 0, stream>>>(W2, Bb2);
  prep_encin<<<(Vsz * 2048) / 4, 256, 0, stream>>>(emb, eWih, ebih, ebhh, encInP);
  prep_dbias<<<8, 256, 0, stream>>>(dbih, dbhh, dbiasP);

  const size_t GF = GFRAGC2;  // f16 stride per step buffer

  // encoder: CH gates steps into rolling frag buffers, then one batched blend
  for (int c = 0; c < Ssz / CH; ++c) {
    for (int s = 0; s < CH; ++s) {
      int t = c * CH + s;
      const f16* in = (t == 0) ? hZero : hBuf + (size_t)((t - 1) % CH) * GF;
      gates_mfma<<<512, 256, 0, stream>>>(in, BfE, encInP, input, t,
                                          hBuf + (size_t)s * GF, cE);
    }
    blend_big<<<8 * 8 * 4 * CH, 256, 0, stream>>>(hBuf, Bb1,
                                                  b1 + (size_t)(c * CH) * Wsz,
                                                  Wsz, Ssz * Wsz);
  }
  // decoder init: c0 = last encoder h (hi+lo), h0 = 0, mask = 0
  dec_cinit<<<(Bsz * Hsz) / 256, 256, 0, stream>>>(
      hBuf + (size_t)((Ssz - 1) % CH) * GF, cE);

  // decoder: gates x CH -> batched blend -> fused chunk sampling
  for (int c = 0; c < Lsz / CH; ++c) {
    for (int s = 0; s < CH; ++s) {
      int k = c * CH + s;
      const f16* in = (k == 0) ? hZero : hBuf + (size_t)((k - 1) % CH) * GF;
      gates_mfma<<<512, 256, 0, stream>>>(in, BfD, dbiasP, nullptr, 0,
                                          hBuf + (size_t)s * GF, cE);
    }
    blend_big<<<8 * 8 * 4 * CH, 256, 0, stream>>>(hBuf, Bb2, b2c,
                                                  Bsz * Wsz, Wsz);
    sample_chunk<<<Bsz, 576, 0, stream>>>(b1, b2c, vt, maskp, outF,
                                          outF + (size_t)Bsz * Lsz * Ssz,
                                          c * CH);
  }
}

// Round 17
// 3288.908 us; speedup vs baseline: 1.0825x; 1.0825x over previous
//
#include <hip/hip_runtime.h>
#include <cstdint>

// Problem constants
#define Bsz 2048
#define Ssz 50
#define Esz 256
#define Hsz 512
#define Wsz 256
#define Lsz 50
#define Vsz 51
#define KI 16    // paired k-iterations (each covers hi[kc], lo[kc+16])
#define CH 10    // steps per blend/sample chunk
#define GFRAGC2 ((size_t)32 * 128 * 512)  // f16 elems per h/W gates pack (4MB)

// JAX RNG semantics: 1 = threefry_partitionable (jax >= 0.4.36 default), 0 = original
#define JAX_THREEFRY_PARTITIONABLE 1

typedef _Float16 f16;
typedef _Float16 f16x8 __attribute__((ext_vector_type(8)));
typedef float f32x4 __attribute__((ext_vector_type(4)));

// ---------------- threefry2x32 (20 rounds), key words (k0,k1) ----------------
__host__ __device__ __forceinline__ void threefry2x32_hd(
    unsigned k0, unsigned k1, unsigned x0, unsigned x1,
    unsigned& o0, unsigned& o1) {
  unsigned ks2 = k0 ^ k1 ^ 0x1BD11BDAu;
  x0 += k0; x1 += k1;
#define TF_RND(r) { x0 += x1; x1 = (x1 << (r)) | (x1 >> (32 - (r))); x1 ^= x0; }
  TF_RND(13) TF_RND(15) TF_RND(26) TF_RND(6)
  x0 += k1; x1 += ks2 + 1u;
  TF_RND(17) TF_RND(29) TF_RND(16) TF_RND(24)
  x0 += ks2; x1 += k0 + 2u;
  TF_RND(13) TF_RND(15) TF_RND(26) TF_RND(6)
  x0 += k0; x1 += k1 + 3u;
  TF_RND(17) TF_RND(29) TF_RND(16) TF_RND(24)
  x0 += k1; x1 += ks2 + 4u;
  TF_RND(13) TF_RND(15) TF_RND(26) TF_RND(6)
  x0 += ks2; x1 += k0 + 5u;
#undef TF_RND
  o0 = x0; o1 = x1;
}

// ---- prep: gates W pack, dual-acc fp16x3 layout ----
// dst[(kc*128 + ntile)*512 + l*8 + e]: kc in [0,16) = Whi, kc in [16,32) =
// Wlo*2048 (same k range).  k = (kc&15)*32 + kg*8 + e; n' = j*4+g.
__global__ __launch_bounds__(512) void prep_gfrag(const float* __restrict__ Whh,
                                                  f16* __restrict__ dst) {
  int blk = blockIdx.x;            // ntile*32 + kc   (grid 128*32 = 4096)
  int ntile = blk >> 5, kc = blk & 31;
  int t = threadIdx.x;             // 512 = l*8 + e
  int l = t >> 3, e = t & 7;
  int c = l & 15, kg = l >> 4;
  int n = ntile * 16 + c;          // n' in [0,2048)
  int k = (kc & 15) * 32 + kg * 8 + e;
  int j = n >> 2, g = n & 3;
  float w = Whh[(size_t)(g * 512 + j) * 512 + k];
  f16 hi = (f16)w;
  float lo = w - (float)hi;
  f16 val = (kc < 16) ? hi : (f16)(lo * 2048.0f);
  dst[((size_t)kc * 128 + ntile) * 512 + t] = val;
}

// ---- prep: blend W pack: [kc 0..31][wtile 0..15][512]; kc>=16 = Wlo*2048 ----
__global__ __launch_bounds__(512) void prep_bfrag(const float* __restrict__ Wm,
                                                  f16* __restrict__ dst) {
  int blk = blockIdx.x;            // wtile*32 + kc   (grid 16*32 = 512)
  int wtile = blk >> 5, kc = blk & 31;
  int t = threadIdx.x;
  int l = t >> 3, e = t & 7;
  int c = l & 15, kg = l >> 4;
  int n = wtile * 16 + c;          // w in [0,256)
  int k = (kc & 15) * 32 + kg * 8 + e;
  float w = Wm[(size_t)n * 512 + k];
  f16 hi = (f16)w;
  float lo = w - (float)hi;
  f16 val = (kc < 16) ? hi : (f16)(lo * 2048.0f);
  dst[((size_t)kc * 16 + wtile) * 512 + t] = val;
}

// ---------------- prep: encInP[v][j*4+g] = emb[v].Wih[g*512+j] + bih + bhh ---
__global__ __launch_bounds__(256) void prep_encin(
    const float* __restrict__ emb, const float* __restrict__ Wih,
    const float* __restrict__ bih, const float* __restrict__ bhh,
    float* __restrict__ encInP) {
  int wid = blockIdx.x * 4 + (threadIdx.x >> 6);
  int lane = threadIdx.x & 63;
  if (wid >= Vsz * 2048) return;
  int v = wid >> 11, col = wid & 2047;
  float4 e = ((const float4*)emb)[v * 64 + lane];
  float4 w = ((const float4*)Wih)[col * 64 + lane];
  float d = e.x * w.x + e.y * w.y + e.z * w.z + e.w * w.w;
  for (int off = 32; off; off >>= 1) d += __shfl_xor(d, off);
  if (lane == 0) {
    int g = col >> 9, j = col & 511;
    encInP[(size_t)v * 2048 + j * 4 + g] = d + bih[col] + bhh[col];
  }
}

// ---------------- prep: dbiasP[j*4+g] = dec_bih + dec_bhh ----------------
__global__ __launch_bounds__(256) void prep_dbias(const float* __restrict__ a,
                                                  const float* __restrict__ b,
                                                  float* __restrict__ dst) {
  int col = blockIdx.x * 256 + threadIdx.x;  // < 2048
  int g = col >> 9, j = col & 511;
  dst[j * 4 + g] = a[col] + b[col];
}

// ---------------- fused gates MFMA GEMM + LSTM cell (r12/r8 config) ----------
// Dual-acc fp16x3: acc1 += hi*Whi + lo*Whi, acc2 += hi*(Wlo*2048);
// C = acc1 + acc2*2^-11.  Tile 64b x 128n', grid 512 = 2 blocks/CU -- the
// best-measured gates config (r12 3342 vs A4B4's r13 3372 / r15 3523).
// Block: 4 waves (2m x 2n); wave = 32b x 64n'.  XCD swizzle: XCD x owns
// b-rows [256x,256x+256) (A producer/consumer L2-local across steps).
__global__ __launch_bounds__(256, 2) void gates_mfma(
    const f16* __restrict__ Afrag,   // h16' [32 kc][128 mt][64 lane][8]
    const f16* __restrict__ Bfrag,   // W'   [32 kc][128 nt][64 lane][8]
    const float* __restrict__ addtab, const int* __restrict__ input, int tstep,
    f16* __restrict__ Aout,          // next h16', same layout
    float* __restrict__ cio) {       // [2048][512] f32
  __shared__ float Cst[64][132];
  const int t = threadIdx.x;
  const int lane = t & 63;
  const int wid = t >> 6;
  const int wm = wid >> 1, wn = wid & 1;
  const int bid = blockIdx.x;
  const int xcd = bid & 7, loc = bid >> 3;          // loc in [0,64)
  const int mblk = xcd * 4 + (loc >> 4);            // 0..31 (64-b tiles)
  const int nblk = loc & 15;                        // 0..15 (128-n' tiles)

  const f16* Ab = Afrag + (size_t)(mblk * 4 + wm * 2) * 512 + lane * 8;
  const f16* Bb = Bfrag + (size_t)(nblk * 8 + wn * 4) * 512 + lane * 8;

  f32x4 acc1[2][4], acc2[2][4];
  {
    f32x4 z = {0.f, 0.f, 0.f, 0.f};
#pragma unroll
    for (int i = 0; i < 2; ++i)
#pragma unroll
      for (int j = 0; j < 4; ++j) { acc1[i][j] = z; acc2[i][j] = z; }
  }

  f16x8 pah[2], pal[2], pbh[4], pbl[4];
  f16x8 qah[2], qal[2], qbh[4], qbl[4];

#define GLOAD(AH_, AL_, BH_, BL_, ki_)                                        \
  {                                                                           \
    const f16* ak = Ab + (size_t)(ki_)*65536;                                 \
    const f16* bk = Bb + (size_t)(ki_)*65536;                                 \
    _Pragma("unroll")                                                         \
    for (int q = 0; q < 2; ++q) {                                             \
      AH_[q] = *(const f16x8*)(ak + q * 512);                                 \
      AL_[q] = *(const f16x8*)(ak + (size_t)16 * 65536 + q * 512);            \
    }                                                                         \
    _Pragma("unroll")                                                         \
    for (int q = 0; q < 4; ++q) {                                             \
      BH_[q] = *(const f16x8*)(bk + q * 512);                                 \
      BL_[q] = *(const f16x8*)(bk + (size_t)16 * 65536 + q * 512);            \
    }                                                                         \
  }
#define GMM(AH_, AL_, BH_, BL_)                                               \
  {                                                                           \
    _Pragma("unroll")                                                         \
    for (int mt = 0; mt < 2; ++mt)                                            \
      _Pragma("unroll")                                                       \
      for (int nt = 0; nt < 4; ++nt)                                          \
        acc1[mt][nt] = __builtin_amdgcn_mfma_f32_16x16x32_f16(                \
            AH_[mt], BH_[nt], acc1[mt][nt], 0, 0, 0);                         \
    _Pragma("unroll")                                                         \
    for (int mt = 0; mt < 2; ++mt)                                            \
      _Pragma("unroll")                                                       \
      for (int nt = 0; nt < 4; ++nt)                                          \
        acc1[mt][nt] = __builtin_amdgcn_mfma_f32_16x16x32_f16(                \
            AL_[mt], BH_[nt], acc1[mt][nt], 0, 0, 0);                         \
    _Pragma("unroll")                                                         \
    for (int mt = 0; mt < 2; ++mt)                                            \
      _Pragma("unroll")                                                       \
      for (int nt = 0; nt < 4; ++nt)                                          \
        acc2[mt][nt] = __builtin_amdgcn_mfma_f32_16x16x32_f16(                \
            AH_[mt], BL_[nt], acc2[mt][nt], 0, 0, 0);                         \
  }

  GLOAD(pah, pal, pbh, pbl, 0)
#pragma unroll 1
  for (int ki = 0; ki < KI; ki += 2) {
    GLOAD(qah, qal, qbh, qbl, ki + 1)
    GMM(pah, pal, pbh, pbl)
    if (ki + 2 < KI) GLOAD(pah, pal, pbh, pbl, ki + 2)
    GMM(qah, qal, qbh, qbl)
  }
#undef GLOAD
#undef GMM

  // ---- epilogue: combine accs, restage via LDS (Cst 34KB; 2 blocks/CU) ----
#pragma unroll
  for (int mt = 0; mt < 2; ++mt)
#pragma unroll
    for (int nt = 0; nt < 4; ++nt)
#pragma unroll
      for (int rg = 0; rg < 4; ++rg)
        Cst[wm * 32 + mt * 16 + (lane >> 4) * 4 + rg]
           [wn * 64 + nt * 16 + (lane & 15)] =
            acc1[mt][nt][rg] + acc2[mt][nt][rg] * (1.0f / 2048.0f);
  __syncthreads();

  const int bloc = t & 63, jg = t >> 6;
  const int bg = mblk * 64 + bloc;
  const float* arow = input
      ? addtab + (size_t)input[(size_t)bg * Ssz + tstep] * 2048
      : addtab;

  const int j0 = nblk * 32 + jg * 8;   // 8 j's per thread
  float* cp = cio + (size_t)bg * 512 + j0;
  float4 cv0 = *(const float4*)(cp);
  float4 cv1 = *(const float4*)(cp + 4);
  float cin[8] = {cv0.x, cv0.y, cv0.z, cv0.w, cv1.x, cv1.y, cv1.z, cv1.w};
  float cn[8], hv[8];
#pragma unroll
  for (int jj = 0; jj < 8; ++jj) {
    float4 gq = *(const float4*)(&Cst[bloc][jg * 32 + jj * 4]);
    float4 av = *(const float4*)(arow + (size_t)(j0 + jj) * 4);
    float gi = gq.x + av.x;
    float gf = gq.y + av.y;
    float gg = gq.z + av.z;
    float go = gq.w + av.w;
    float si = 1.0f / (1.0f + expf(-gi));
    float sf = 1.0f / (1.0f + expf(-gf));
    float sg = tanhf(gg);
    float so = 1.0f / (1.0f + expf(-go));
    float c2 = sf * cin[jj] + si * sg;
    cn[jj] = c2;
    hv[jj] = so * tanhf(c2);
  }
  *(float4*)(cp)     = make_float4(cn[0], cn[1], cn[2], cn[3]);
  *(float4*)(cp + 4) = make_float4(cn[4], cn[5], cn[6], cn[7]);

  f16x8 hi8, lo8;
#pragma unroll
  for (int jj = 0; jj < 8; ++jj) {
    f16 hi = (f16)hv[jj];
    hi8[jj] = hi;
    lo8[jj] = (f16)(hv[jj] - (float)hi);
  }
  const int kcH = j0 >> 5;             // 0..15
  const int kg = (j0 >> 3) & 3;
  size_t base = (((size_t)kcH * 128 + (bg >> 4)) * 64 + kg * 16 + (bg & 15)) * 8;
  *(f16x8*)(Aout + base)                       = hi8;  // kc 0..15: hi
  *(f16x8*)(Aout + base + (size_t)16 * 65536)  = lo8;  // kc 16..31: lo
}

// ---------------- batched blend MFMA: CH steps in one dispatch ---------------
// Dual-acc fp16x3.  XCD mapping ALIGNED with gates h-row ownership.
// Epilogue stores exp(2*acc) (bit-identical downstream: both outputs are
// consumed ONLY as exp(2*x); same f32 bits -> same __expf bits).
__global__ __launch_bounds__(256) void blend_big(
    const f16* __restrict__ hChunk, const f16* __restrict__ Wb,
    float* __restrict__ outBase, int stepStride, int rowStride) {
  const int t = threadIdx.x, lane = t & 63, wid = t >> 6;
  const int wm = wid >> 1, wn = wid & 1;
  const int bid = blockIdx.x;
  const int xcd = bid & 7;
  const int r1 = bid >> 3;
  const int nblk = r1 & 7;             // 0..7  (32-w tiles)
  const int r2 = r1 >> 3;
  const int mrem = r2 & 3;
  const int s = r2 >> 2;               // step within chunk
  const int mblkL = xcd * 4 + mrem;    // 0..31 (64-b tiles), XCD-aligned
  const f16* Ab = hChunk + (size_t)s * GFRAGC2
                + (size_t)(mblkL * 4 + wm * 2) * 512 + lane * 8;
  const f16* Bb = Wb + (size_t)(nblk * 2 + wn) * 512 + lane * 8;

  f32x4 acc1[2], acc2[2];
  {
    f32x4 z = {0.f, 0.f, 0.f, 0.f};
    acc1[0] = z; acc1[1] = z; acc2[0] = z; acc2[1] = z;
  }
  f16x8 pah[2], pal[2], pbh, pbl, qah[2], qal[2], qbh, qbl;

#define BLOAD(AH_, AL_, BH_, BL_, ki_)                                        \
  {                                                                           \
    const f16* ak = Ab + (size_t)(ki_)*65536;                                 \
    const f16* bk = Bb + (size_t)(ki_)*8192;                                  \
    _Pragma("unroll")                                                         \
    for (int q = 0; q < 2; ++q) {                                             \
      AH_[q] = *(const f16x8*)(ak + q * 512);                                 \
      AL_[q] = *(const f16x8*)(ak + (size_t)16 * 65536 + q * 512);            \
    }                                                                         \
    BH_ = *(const f16x8*)(bk);                                                \
    BL_ = *(const f16x8*)(bk + (size_t)16 * 8192);                            \
  }
#define BMM(AH_, AL_, BH_, BL_)                                               \
  {                                                                           \
    _Pragma("unroll")                                                         \
    for (int mt = 0; mt < 2; ++mt)                                            \
      acc1[mt] = __builtin_amdgcn_mfma_f32_16x16x32_f16(                      \
          AH_[mt], BH_, acc1[mt], 0, 0, 0);                                   \
    _Pragma("unroll")                                                         \
    for (int mt = 0; mt < 2; ++mt)                                            \
      acc1[mt] = __builtin_amdgcn_mfma_f32_16x16x32_f16(                      \
          AL_[mt], BH_, acc1[mt], 0, 0, 0);                                   \
    _Pragma("unroll")                                                         \
    for (int mt = 0; mt < 2; ++mt)                                            \
      acc2[mt] = __builtin_amdgcn_mfma_f32_16x16x32_f16(                      \
          AH_[mt], BL_, acc2[mt], 0, 0, 0);                                   \
  }

  BLOAD(pah, pal, pbh, pbl, 0)
#pragma unroll 1
  for (int ki = 0; ki < KI; ki += 2) {
    BLOAD(qah, qal, qbh, qbl, ki + 1)
    BMM(pah, pal, pbh, pbl)
    if (ki + 2 < KI) BLOAD(pah, pal, pbh, pbl, ki + 2)
    BMM(qah, qal, qbh, qbl)
  }
#undef BLOAD
#undef BMM

  const int r = lane & 15, rg4 = (lane >> 4) * 4;
  float* ob = outBase + (size_t)s * stepStride;
#pragma unroll
  for (int mt = 0; mt < 2; ++mt)
#pragma unroll
    for (int rg = 0; rg < 4; ++rg) {
      int b = mblkL * 64 + wm * 32 + mt * 16 + rg4 + rg;
      int w = nblk * 32 + wn * 16 + r;
      float val = acc1[mt][rg] + acc2[mt][rg] * (1.0f / 2048.0f);
      ob[(size_t)b * rowStride + w] = __expf(2.0f * val);   // E = e^{2*blend}
    }
}

// ---------------- decoder c0 = last encoder h (reconstruct hi+lo) ------------
__global__ __launch_bounds__(256) void dec_cinit(const f16* __restrict__ hE,
                                                 float* __restrict__ cD) {
  int idx = blockIdx.x * 256 + threadIdx.x;  // < 2048*512
  int b = idx >> 9, j = idx & 511;
  size_t base = (((size_t)(j >> 5) * 128 + (b >> 4)) * 64
                 + ((j >> 3) & 3) * 16 + (b & 15)) * 8 + (j & 7);
  cD[idx] = (float)hE[base] + (float)hE[base + (size_t)16 * 65536];
}

// ---------------- fused chunk sampling v6: r12 structure + pre-exp inputs ----
// EXACT r12 structure (512 thr / 8 waves: waves 0..6 score s+=7, wave 7
// samples -- measured 164us @ 88% VALUBusy; r16's 576-thr 9-wave variant
// regressed to 215us via occupancy loss).  Inputs b1/b2c are pre-exp'd in
// blend (same f32 bits -> identical values), so staging is a pure copy and
// per-step e2 is 4 plain loads: strictly less VALU work, same structure.
__global__ __launch_bounds__(512) void sample_chunk(
    const float* __restrict__ b1, const float* __restrict__ b2c,
    const float* __restrict__ vt, unsigned long long* __restrict__ mask,
    float* __restrict__ probs, float* __restrict__ tour, int k0) {
  __shared__ float e1s[Ssz * Wsz];   // 50 KB: e^{2*b1} (already exp'd)
  __shared__ float scbuf[2][52];
  const int t = threadIdx.x, b = blockIdx.x;
  const int wid = t >> 6, lane = t & 63;
  {
    const float4* src = (const float4*)(b1 + (size_t)b * Ssz * Wsz);
    for (int i = t; i < (Ssz * Wsz) / 4; i += 512)
      ((float4*)e1s)[i] = src[i];
  }
  const float vtr0 = vt[lane], vtr1 = vt[lane + 64];
  const float vtr2 = vt[lane + 128], vtr3 = vt[lane + 192];
  unsigned long long m = (wid == 7) ? mask[b] : 0ull;
  __syncthreads();

#define SCORE_ROWS(step_, dst_)                                               \
  {                                                                           \
    const float* b2p = b2c + ((size_t)(step_) * Bsz + b) * Wsz;               \
    float e20 = b2p[lane];                                                    \
    float e21 = b2p[lane + 64];                                               \
    float e22 = b2p[lane + 128];                                              \
    float e23 = b2p[lane + 192];                                              \
    for (int s = wid; s < Ssz; s += 7) {                                      \
      const float* row = e1s + s * Wsz;                                       \
      float r0 = __frcp_rn(fmaf(row[lane], e20, 1.0f));                       \
      float v = vtr0 * fmaf(-2.0f, r0, 1.0f);                                 \
      float r1 = __frcp_rn(fmaf(row[lane + 64], e21, 1.0f));                  \
      v += vtr1 * fmaf(-2.0f, r1, 1.0f);                                      \
      float r2 = __frcp_rn(fmaf(row[lane + 128], e22, 1.0f));                 \
      v += vtr2 * fmaf(-2.0f, r2, 1.0f);                                      \
      float r3 = __frcp_rn(fmaf(row[lane + 192], e23, 1.0f));                 \
      v += vtr3 * fmaf(-2.0f, r3, 1.0f);                                      \
      for (int off = 32; off; off >>= 1) v += __shfl_xor(v, off);             \
      if (lane == 0) (dst_)[s] = v;                                           \
    }                                                                         \
  }

  // prologue: waves 0..6 compute step 0 into scbuf[0]
  if (wid < 7) SCORE_ROWS(0, scbuf[0])
  __syncthreads();

#pragma unroll 1
  for (int kk = 0; kk < CH; ++kk) {
    if (wid < 7) {
      if (kk + 1 < CH) SCORE_ROWS(kk + 1, scbuf[(kk + 1) & 1])
    } else {
      const float* sc = scbuf[kk & 1];
      const int stepk = k0 + kk;
      float x = (lane < Ssz) ? sc[lane] : -INFINITY;
      if (lane < Ssz && ((m >> lane) & 1ull)) x = -100000.0f;
      float mv = x;
      for (int off = 32; off; off >>= 1) mv = fmaxf(mv, __shfl_xor(mv, off));
      float sh = x - mv;
      float e = (lane < Ssz) ? expf(sh) : 0.f;
      float ssum = e;
      for (int off = 32; off; off >>= 1) ssum += __shfl_xor(ssum, off);
      float lg = logf(ssum);
      float logp = sh - lg;
      if (lane < Ssz) probs[(size_t)b * (Lsz * Ssz) + stepk * Ssz + lane] = logp;

      unsigned kA, kB;
#if JAX_THREEFRY_PARTITIONABLE
      threefry2x32_hd(0u, 42u, 0u, (unsigned)stepk, kA, kB);
#else
      {
        unsigned a0, a1, c0, c1;
        int k = stepk;
        if (k < 25) {
          threefry2x32_hd(0u, 42u, 2u * k,      2u * k + 50u, a0, a1); kA = a0;
          threefry2x32_hd(0u, 42u, 2u * k + 1u, 2u * k + 51u, c0, c1); kB = c0;
        } else {
          threefry2x32_hd(0u, 42u, 2u * k - 50u, 2u * k,      a0, a1); kA = a1;
          threefry2x32_hd(0u, 42u, 2u * k - 49u, 2u * k + 1u, c0, c1); kB = c1;
        }
      }
#endif
      float val = -INFINITY;
      if (lane < Ssz) {
        unsigned j = (unsigned)(b * Ssz + lane);
        unsigned o0, o1, bits;
#if JAX_THREEFRY_PARTITIONABLE
        threefry2x32_hd(kA, kB, 0u, j, o0, o1);
        bits = o0 ^ o1;
#else
        if (j < 51200u) { threefry2x32_hd(kA, kB, j, j + 51200u, o0, o1); bits = o0; }
        else           { threefry2x32_hd(kA, kB, j - 51200u, j, o0, o1); bits = o1; }
#endif
        float f = __uint_as_float((bits >> 9) | 0x3F800000u) - 1.0f;
        float u = fmaxf(1.17549435e-38f, f + 1.17549435e-38f);
        val = logp - logf(-logf(u));
      }
      int idx = lane;
      for (int off = 32; off; off >>= 1) {
        float ov = __shfl_xor(val, off);
        int oi = __shfl_xor(idx, off);
        if (ov > val || (ov == val && oi < idx)) { val = ov; idx = oi; }
      }
      if (lane == 0) tour[(size_t)b * Lsz + stepk] = (float)idx;
      m |= (1ull << idx);
    }
    __syncthreads();
  }
#undef SCORE_ROWS
  if (wid == 7 && lane == 0) mask[b] = m;
}

extern "C" void kernel_launch(void* const* d_in, const int* in_sizes, int n_in,
                              void* d_out, int out_size, void* d_ws, size_t ws_size,
                              hipStream_t stream) {
  (void)in_sizes; (void)n_in; (void)out_size; (void)ws_size;
  const int*   input = (const int*)d_in[0];
  const float* emb   = (const float*)d_in[1];
  const float* eWih  = (const float*)d_in[2];
  const float* eWhh  = (const float*)d_in[3];
  const float* ebih  = (const float*)d_in[4];
  const float* ebhh  = (const float*)d_in[5];
  /* d_in[6] dec_Wih unused: decoder input is always zero */
  const float* dWhh  = (const float*)d_in[7];
  const float* dbih  = (const float*)d_in[8];
  const float* dbhh  = (const float*)d_in[9];
  const float* W1    = (const float*)d_in[10];
  const float* W2    = (const float*)d_in[11];
  const float* vt    = (const float*)d_in[12];
  float* outF = (float*)d_out;

  float* wsf = (float*)d_ws;
  size_t o = 0;
  const size_t BFRAG = (size_t)32 * 16 * 512;   // f16 count (blend W pack)
  f16* BfE = (f16*)(wsf + o); o += GFRAGC2 / 2;  // enc gates W pack (4MB)
  f16* BfD = (f16*)(wsf + o); o += GFRAGC2 / 2;  // dec gates W pack
  f16* Bb1 = (f16*)(wsf + o); o += BFRAG / 2;    // W1 blend pack
  f16* Bb2 = (f16*)(wsf + o); o += BFRAG / 2;    // W2 blend pack
  float* encInP = wsf + o; o += (size_t)Vsz * 2048;
  float* dbiasP = wsf + o; o += 2048;
  f16* hZero = (f16*)(wsf + o); o += GFRAGC2 / 2;          // zero h frags
  f16* hBuf  = (f16*)(wsf + o); o += CH * (GFRAGC2 / 2);   // CH rolling h frags
  float* cE  = wsf + o; o += (size_t)Bsz * Hsz;            // enc c, then dec c
  float* b2c = wsf + o; o += (size_t)CH * Bsz * Wsz;       // dec b2 chunk (exp'd)
  float* b1  = wsf + o; o += (size_t)Bsz * Ssz * Wsz;      // enc blend (exp'd)
  unsigned long long* maskp = (unsigned long long*)(wsf + o); o += Bsz * 2;

  hipMemsetAsync(hZero, 0, GFRAGC2 * 2, stream);
  hipMemsetAsync(cE, 0, (size_t)Bsz * Hsz * 4, stream);
  hipMemsetAsync(maskp, 0, (size_t)Bsz * 8, stream);

  prep_gfrag<<<128 * 32, 512, 0, stream>>>(eWhh, BfE);
  prep_gfrag<<<128 * 32, 512, 0, stream>>>(dWhh, BfD);
  prep_bfrag<<<16 * 32, 512, 0, stream>>>(W1, Bb1);
  prep_bfrag<<<16 * 32, 512, 0, stream>>>(W2, Bb2);
  prep_encin<<<(Vsz * 2048) / 4, 256, 0, stream>>>(emb, eWih, ebih, ebhh, encInP);
  prep_dbias<<<8, 256, 0, stream>>>(dbih, dbhh, dbiasP);

  const size_t GF = GFRAGC2;  // f16 stride per step buffer

  // encoder: CH gates steps into rolling frag buffers, then one batched blend
  for (int c = 0; c < Ssz / CH; ++c) {
    for (int s = 0; s < CH; ++s) {
      int t = c * CH + s;
      const f16* in = (t == 0) ? hZero : hBuf + (size_t)((t - 1) % CH) * GF;
      gates_mfma<<<512, 256, 0, stream>>>(in, BfE, encInP, input, t,
                                          hBuf + (size_t)s * GF, cE);
    }
    blend_big<<<8 * 8 * 4 * CH, 256, 0, stream>>>(hBuf, Bb1,
                                                  b1 + (size_t)(c * CH) * Wsz,
                                                  Wsz, Ssz * Wsz);
  }
  // decoder init: c0 = last encoder h (hi+lo), h0 = 0, mask = 0
  dec_cinit<<<(Bsz * Hsz) / 256, 256, 0, stream>>>(
      hBuf + (size_t)((Ssz - 1) % CH) * GF, cE);

  // decoder: gates x CH -> batched blend -> fused chunk sampling
  for (int c = 0; c < Lsz / CH; ++c) {
    for (int s = 0; s < CH; ++s) {
      int k = c * CH + s;
      const f16* in = (k == 0) ? hZero : hBuf + (size_t)((k - 1) % CH) * GF;
      gates_mfma<<<512, 256, 0, stream>>>(in, BfD, dbiasP, nullptr, 0,
                                          hBuf + (size_t)s * GF, cE);
    }
    blend_big<<<8 * 8 * 4 * CH, 256, 0, stream>>>(hBuf, Bb2, b2c,
                                                  Bsz * Wsz, Wsz);
    sample_chunk<<<Bsz, 512, 0, stream>>>(b1, b2c, vt, maskp, outF,
                                          outF + (size_t)Bsz * Lsz * Ssz,
                                          c * CH);
  }
}